// Round 2
// baseline (472.064 us; speedup 1.0000x reference)
//
#include <hip/hip_runtime.h>
#include <hip/hip_cooperative_groups.h>

namespace cg = cooperative_groups;

#define N_NODES 10000
#define NE      80000
#define H       32
#define VD0     2048
#define VD1     256

// fixed-capacity edge buckets (degree is Binomial(80000,1e-4), max ~23 on this
// data; EDGE_CAP=32 with a guaranteed-correct scalar slow-path on overflow)
#define EDGE_CAP 32

// ---- stage A (prep) units: one block each -------------------------------
#define A_MLP    40                        // node MLP, 256 nodes/block
#define A_NC0    2500                      // normconv graph0, 4 nodes/block
#define A_NC1    2500                      // normconv graph1, 4 nodes/block
#define A_UNITS  (A_MLP + A_NC0 + A_NC1)   // 5040
#define ZERO_BLOCKS 79                     // ceil(2*N_NODES/256) for cur zeroing

// ---- stage C (edge) units: one block each -------------------------------
// graph0: 8 K-phases of 256 elems (512 B). phase = unit&7 -> with round-robin
// block->XCD dispatch each XCD owns ONE 5.12 MB slice of vn0 (fits 4 MiB L2
// after warm reuse; srcs are reused ~8x within the same XCD). uint2/lane.
#define C_PHASES 8
#define C_G0     (C_PHASES * 2500)         // 20000 graph0 units (4 dsts/block)
#define C_UNITS  (C_G0 + 2500)             // + graph1: 4 dsts/block, 512B rows

// ---------------------------------------------------------------------------
// bf16 helpers
// ---------------------------------------------------------------------------
__device__ inline unsigned short f2bf_rne(float f) {
    unsigned int u = __float_as_uint(f);
    u += 0x7fffu + ((u >> 16) & 1u);
    return (unsigned short)(u >> 16);
}
__device__ inline float bflo(unsigned int u) { return __uint_as_float(u << 16); }
__device__ inline float bfhi(unsigned int u) { return __uint_as_float(u & 0xffff0000u); }
__device__ inline float bfs(unsigned short u) { return __uint_as_float((unsigned int)u << 16); }

__device__ inline float dot4_bf16(uint2 a, uint2 b) {
    return bflo(a.x) * bflo(b.x) + bfhi(a.x) * bfhi(b.x)
         + bflo(a.y) * bflo(b.y) + bfhi(a.y) * bfhi(b.y);
}

// ---------------------------------------------------------------------------
// param pack shared by all kernels
// ---------------------------------------------------------------------------
struct KP {
    const float* x;
    const float* vis0; const float* vis1;
    const int* ei0; const int* ei1;
    const float* W_in1; const float* b_in1;
    const float* bn_gamma; const float* bn_beta;
    const float* bn_mean; const float* bn_var;
    const float* prelu_a;
    const float* W_in2; const float* b_in2;
    const float* w_node; const float* b_node;
    const float* W_c0; const float* b_c0;
    const float* W_c1; const float* b_c1;
    const float* w_p0; const float* b_p0;
    const float* w_p1; const float* b_p1;
    float* out; float* p0w; float* p1w;
    unsigned short* vn0; unsigned short* vn1;
    uint2* b0; uint2* b1;
    int* cur0; int* cur1;          // cur0,cur1 CONTIGUOUS (zeroed as one range)
};

// ---------------------------------------------------------------------------
// normconv body: vn[node] = bf16( vis[node] * rsqrt(||vis[node]||^2 + 1e-8) )
// one 64-lane wave per node, row held in registers between passes
// ---------------------------------------------------------------------------
template <int VD>
__device__ inline void normconv_node(const float* __restrict__ vis,
                                     unsigned short* __restrict__ vn,
                                     int node, int lane)
{
    const float4* v = (const float4*)(vis + (size_t)node * VD);
    float4 f[VD / 256];
    float acc = 0.f;
    #pragma unroll
    for (int it = 0; it < VD / 256; it++) {
        f[it] = v[it * 64 + lane];
        acc += f[it].x * f[it].x + f[it].y * f[it].y + f[it].z * f[it].z + f[it].w * f[it].w;
    }
    #pragma unroll
    for (int o = 32; o; o >>= 1) acc += __shfl_xor(acc, o);
    const float inv = rsqrtf(acc + 1e-8f);
    ushort4* o4 = (ushort4*)(vn + (size_t)node * VD);
    #pragma unroll
    for (int it = 0; it < VD / 256; it++) {
        ushort4 r;
        r.x = f2bf_rne(f[it].x * inv);
        r.y = f2bf_rne(f[it].y * inv);
        r.z = f2bf_rne(f[it].z * inv);
        r.w = f2bf_rne(f[it].w * inv);
        o4[it * 64 + lane] = r;
    }
}

// ---------------------------------------------------------------------------
// STAGE A unit: [0,40) node MLP; [40,2540) normconv0; [2540,5040) normconv1
// (no thread 'return' anywhere -- persistent-kernel safe)
// ---------------------------------------------------------------------------
__device__ inline void stageA_unit(const KP& p, int u, int t)
{
    if (u < A_MLP) {
        __shared__ float sW1[9 * H];
        __shared__ float sW2[H * H];
        __shared__ float sU0[H], sU1[H], sWn[H];
        __shared__ float sB1[H], sB2[H], sSc[H], sSh[H];
        __shared__ float sC;

        for (int i = t; i < 9 * H; i += 256) sW1[i] = p.W_in1[i];
        for (int i = t; i < H * H; i += 256) sW2[i] = p.W_in2[i];
        if (t < H) {
            sB1[t] = p.b_in1[t];
            sB2[t] = p.b_in2[t];
            float sc = p.bn_gamma[t] * rsqrtf(p.bn_var[t] + 1e-5f);
            sSc[t] = sc;
            sSh[t] = p.bn_beta[t] - p.bn_mean[t] * sc;
            sWn[t] = p.w_node[t];
            float u0 = 0.f, u1 = 0.f;
            for (int j = 0; j < H; j++) {
                u0 += p.W_c0[t * H + j] * p.w_p0[j];
                u1 += p.W_c1[t * H + j] * p.w_p1[j];
            }
            sU0[t] = u0; sU1[t] = u1;
        }
        if (t == 0) {
            float c0 = p.b_p0[0], c1 = p.b_p1[0];
            for (int j = 0; j < H; j++) { c0 += p.b_c0[j] * p.w_p0[j]; c1 += p.b_c1[j] * p.w_p1[j]; }
            sC = c0 + c1 + p.b_node[0];
        }
        __syncthreads();

        const float a = p.prelu_a[0];
        const int n = u * 256 + t;
        if (n < N_NODES) {
            float xi[9];
            #pragma unroll
            for (int i = 0; i < 9; i++) xi[i] = p.x[n * 9 + i];

            float tt[H];
            #pragma unroll
            for (int j = 0; j < H; j++) {
                float s = sB1[j];
                #pragma unroll
                for (int i = 0; i < 9; i++) s += xi[i] * sW1[i * H + j];
                s = s * sSc[j] + sSh[j];
                tt[j] = s >= 0.f ? s : a * s;
            }

            float ns = 0.f, p0 = 0.f, p1 = 0.f;
            #pragma unroll
            for (int k = 0; k < H; k++) {
                float h = sB2[k];
                #pragma unroll
                for (int j = 0; j < H; j++) h += tt[j] * sW2[j * H + k];
                ns += h * sWn[k];
                p0 += h * sU0[k];
                p1 += h * sU1[k];
            }
            p.out[n] = ns + sC;
            p.p0w[n] = p0;
            p.p1w[n] = p1;
        }
        __syncthreads();   // guard LDS reuse if a block ever runs 2 MLP units
    } else if (u < A_MLP + A_NC0) {
        const int node = (u - A_MLP) * 4 + (t >> 6);
        normconv_node<VD0>(p.vis0, p.vn0, node, t & 63);
    } else {
        const int node = (u - A_MLP - A_NC0) * 4 + (t >> 6);
        normconv_node<VD1>(p.vis1, p.vn1, node, t & 63);
    }
}

// ---------------------------------------------------------------------------
// STAGE B: bucket-append scatter, one edge slot (both graphs).
// Entry = {src row byte offset, p_weight[src]}. Overflow -> exact slow path.
// ---------------------------------------------------------------------------
__device__ inline void stageB_edge(const KP& p, int e)
{
    {
        const int s = p.ei0[e];
        const int d = p.ei0[NE + e];
        const int pos = atomicAdd(&p.cur0[d], 1);
        if (pos < EDGE_CAP) {
            p.b0[d * EDGE_CAP + pos] = make_uint2((unsigned)(s * (VD0 * 2)),
                                                  __float_as_uint(p.p0w[s]));
        } else {
            const unsigned short* a = p.vn0 + (size_t)s * VD0;
            const unsigned short* c = p.vn0 + (size_t)d * VD0;
            float acc = 0.f;
            for (int i = 0; i < VD0; i++) acc += bfs(a[i]) * bfs(c[i]);
            atomicAdd(&p.out[d], acc * p.p0w[s]);
        }
    }
    {
        const int s = p.ei1[e];
        const int d = p.ei1[NE + e];
        const int pos = atomicAdd(&p.cur1[d], 1);
        if (pos < EDGE_CAP) {
            p.b1[d * EDGE_CAP + pos] = make_uint2((unsigned)(s * (VD1 * 2)),
                                                  __float_as_uint(p.p1w[s]));
        } else {
            const unsigned short* a = p.vn1 + (size_t)s * VD1;
            const unsigned short* c = p.vn1 + (size_t)d * VD1;
            float acc = 0.f;
            for (int i = 0; i < VD1; i++) acc += bfs(a[i]) * bfs(c[i]);
            atomicAdd(&p.out[d], acc * p.p1w[s]);
        }
    }
}

// ---------------------------------------------------------------------------
// STAGE C unit: graph0 [0,20000) = (phase = u&7, 4 dsts/block, uint2/lane,
// 8-edge predicated pipeline); graph1 [20000,22500) = 4 dsts/block, full row.
// ---------------------------------------------------------------------------
__device__ inline void stageC_unit(const KP& p, int u, int t)
{
    const int lane = t & 63;

    if (u < C_G0) {
        const int phase = u & 7;                  // == XCD id (round-robin)
        const int group = u >> 3;
        const int d     = group * 4 + (t >> 6);
        int cnt = p.cur0[d];
        if (cnt <= 0) return;
        cnt = cnt < EDGE_CAP ? cnt : EDGE_CAP;
        const int last = cnt - 1;

        const char* base = (const char*)p.vn0;
        const int koffB  = phase * 512 + lane * 8;     // byte offset into row
        const uint2 dreg = *(const uint2*)(base + d * (VD0 * 2) + koffB);
        const uint2* eb  = p.b0 + d * EDGE_CAP;

        float partial = 0.f;
        for (int j = 0; j < cnt; j += 8) {
            uint2 e[8];
            #pragma unroll
            for (int k = 0; k < 8; k++) {
                int jj = j + k;
                jj = jj > last ? last : jj;
                e[k] = eb[jj];
            }
            uint2 r[8];
            #pragma unroll
            for (int k = 0; k < 8; k++)
                r[k] = *(const uint2*)(base + e[k].x + koffB);
            #pragma unroll
            for (int k = 0; k < 8; k++) {
                const float pw = (j + k <= last) ? __uint_as_float(e[k].y) : 0.f;
                partial += dot4_bf16(dreg, r[k]) * pw;
            }
        }
        #pragma unroll
        for (int o = 32; o; o >>= 1) partial += __shfl_down(partial, o);
        if (lane == 0) atomicAdd(&p.out[d], partial);
    } else {
        const int d = (u - C_G0) * 4 + (t >> 6);
        int cnt = p.cur1[d];
        if (cnt <= 0) return;
        cnt = cnt < EDGE_CAP ? cnt : EDGE_CAP;
        const int last = cnt - 1;

        const char* base = (const char*)p.vn1;
        const int koffB  = lane * 8;
        const uint2 dreg = *(const uint2*)(base + d * (VD1 * 2) + koffB);
        const uint2* eb  = p.b1 + d * EDGE_CAP;

        float partial = 0.f;
        for (int j = 0; j < cnt; j += 8) {
            uint2 e[8];
            #pragma unroll
            for (int k = 0; k < 8; k++) {
                int jj = j + k;
                jj = jj > last ? last : jj;
                e[k] = eb[jj];
            }
            uint2 r[8];
            #pragma unroll
            for (int k = 0; k < 8; k++)
                r[k] = *(const uint2*)(base + e[k].x + koffB);
            #pragma unroll
            for (int k = 0; k < 8; k++) {
                const float pw = (j + k <= last) ? __uint_as_float(e[k].y) : 0.f;
                partial += dot4_bf16(dreg, r[k]) * pw;
            }
        }
        #pragma unroll
        for (int o = 32; o; o >>= 1) partial += __shfl_down(partial, o);
        if (lane == 0) atomicAdd(&p.out[d], partial);
    }
}

// ---------------------------------------------------------------------------
// MEGA kernel: persistent cooperative. zero-cur + stage A | sync | B | sync | C
// Grid is a multiple of 8 so u&7 is constant per block chain -> XCD pinning.
// ---------------------------------------------------------------------------
__global__ __launch_bounds__(256, 4) void mega_kernel(KP p)
{
    const int t = threadIdx.x;
    const int b = blockIdx.x;
    const int G = gridDim.x;

    for (int i = b * 256 + t; i < 2 * N_NODES; i += G * 256) p.cur0[i] = 0;
    for (int u = b; u < A_UNITS; u += G) stageA_unit(p, u, t);
    cg::this_grid().sync();
    for (int e = b * 256 + t; e < NE; e += G * 256) stageB_edge(p, e);
    cg::this_grid().sync();
    for (int u = b; u < C_UNITS; u += G) stageC_unit(p, u, t);
}

// ---------------------------------------------------------------------------
// Non-cooperative fallback pipeline (same stage bodies, 3 dispatches)
// ---------------------------------------------------------------------------
__global__ __launch_bounds__(256) void prep2_kernel(KP p)
{
    const int b = blockIdx.x, t = threadIdx.x;
    if (b < ZERO_BLOCKS) {
        const int i = b * 256 + t;
        if (i < 2 * N_NODES) p.cur0[i] = 0;
    } else {
        stageA_unit(p, b - ZERO_BLOCKS, t);
    }
}
__global__ __launch_bounds__(256) void scatter2_kernel(KP p)
{
    const int e = blockIdx.x * 256 + threadIdx.x;
    if (e < NE) stageB_edge(p, e);
}
__global__ __launch_bounds__(256) void edge2_kernel(KP p)
{
    stageC_unit(p, blockIdx.x, threadIdx.x);
}

// ---------------------------------------------------------------------------
// fp32 minimal fallback (only if ws can't hold bf16 rows + buckets)
// ---------------------------------------------------------------------------
template <int VD>
__global__ __launch_bounds__(256) void norm_kernel(const float* __restrict__ vis,
                                                   float* __restrict__ inv)
{
    const int wave = (blockIdx.x * 256 + threadIdx.x) >> 6;
    const int lane = threadIdx.x & 63;
    if (wave >= N_NODES) return;
    const float4* v = (const float4*)(vis + (size_t)wave * VD);
    float acc = 0.f;
    #pragma unroll
    for (int it = 0; it < VD / 256; it++) {
        float4 f = v[lane + it * 64];
        acc += f.x * f.x + f.y * f.y + f.z * f.z + f.w * f.w;
    }
    #pragma unroll
    for (int o = 32; o; o >>= 1) acc += __shfl_down(acc, o);
    if (lane == 0) inv[wave] = rsqrtf(acc + 1e-8f);
}

template <int VD>
__global__ __launch_bounds__(256) void edge_kernel(
    const float* __restrict__ vis, const int* __restrict__ ei,
    const float* __restrict__ inv, const float* __restrict__ pz,
    float* __restrict__ out)
{
    const int wave = (blockIdx.x * 256 + threadIdx.x) >> 6;
    const int lane = threadIdx.x & 63;
    if (wave >= NE) return;
    const int src = ei[wave];
    const int dst = ei[NE + wave];
    const float4* va = (const float4*)(vis + (size_t)src * VD);
    const float4* vb = (const float4*)(vis + (size_t)dst * VD);
    float acc = 0.f;
    #pragma unroll
    for (int it = 0; it < VD / 256; it++) {
        float4 fa = va[lane + it * 64];
        float4 fb = vb[lane + it * 64];
        acc += fa.x * fb.x + fa.y * fb.y + fa.z * fb.z + fa.w * fb.w;
    }
    #pragma unroll
    for (int o = 32; o; o >>= 1) acc += __shfl_down(acc, o);
    if (lane == 0) {
        float w = acc * inv[src] * inv[dst];
        atomicAdd(&out[dst], w * pz[src]);
    }
}

__global__ __launch_bounds__(256) void node_kernel_fb(KP p)
{
    stageA_unit(p, (int)blockIdx.x, (int)threadIdx.x);  // only MLP units launched
}

extern "C" void kernel_launch(void* const* d_in, const int* in_sizes, int n_in,
                              void* d_out, int out_size, void* d_ws, size_t ws_size,
                              hipStream_t stream)
{
    KP hp;
    hp.x        = (const float*)d_in[0];
    hp.vis0     = (const float*)d_in[1];
    hp.vis1     = (const float*)d_in[2];
    hp.ei0      = (const int*)d_in[3];
    hp.ei1      = (const int*)d_in[4];
    hp.W_in1    = (const float*)d_in[5];
    hp.b_in1    = (const float*)d_in[6];
    hp.bn_gamma = (const float*)d_in[7];
    hp.bn_beta  = (const float*)d_in[8];
    hp.bn_mean  = (const float*)d_in[9];
    hp.bn_var   = (const float*)d_in[10];
    hp.prelu_a  = (const float*)d_in[11];
    hp.W_in2    = (const float*)d_in[12];
    hp.b_in2    = (const float*)d_in[13];
    hp.w_node   = (const float*)d_in[14];
    hp.b_node   = (const float*)d_in[15];
    hp.W_c0     = (const float*)d_in[16];
    hp.b_c0     = (const float*)d_in[17];
    hp.W_c1     = (const float*)d_in[18];
    hp.b_c1     = (const float*)d_in[19];
    hp.w_p0     = (const float*)d_in[20];
    hp.b_p0     = (const float*)d_in[21];
    hp.w_p1     = (const float*)d_in[22];
    hp.b_p1     = (const float*)d_in[23];
    hp.out      = (float*)d_out;

    // workspace layout — small arrays FIRST (fp32 fallback needs ~160 KB),
    // every chunk a multiple of 16 B
    char* ws = (char*)d_ws;
    hp.p0w  = (float*)ws;                  ws += N_NODES * 4;
    hp.p1w  = (float*)ws;                  ws += N_NODES * 4;
    float* inv0 = (float*)ws;              ws += N_NODES * 4;
    float* inv1 = (float*)ws;              ws += N_NODES * 4;
    hp.vn0  = (unsigned short*)ws;         ws += (size_t)N_NODES * VD0 * 2;
    hp.vn1  = (unsigned short*)ws;         ws += (size_t)N_NODES * VD1 * 2;
    hp.b0   = (uint2*)ws;                  ws += (size_t)N_NODES * EDGE_CAP * 8;
    hp.b1   = (uint2*)ws;                  ws += (size_t)N_NODES * EDGE_CAP * 8;
    hp.cur0 = (int*)ws;                    ws += N_NODES * 4;   // cur0+cur1
    hp.cur1 = (int*)ws;                    ws += N_NODES * 4;   //   contiguous
    const size_t need = (size_t)(ws - (char*)d_ws);

    if (ws_size >= need) {
        // one-time occupancy query for cooperative grid sizing (not a stream op)
        static int coop = -2;
        if (coop == -2) {
            int nb = 0;
            if (hipOccupancyMaxActiveBlocksPerMultiprocessor(&nb, mega_kernel, 256, 0)
                    == hipSuccess && nb > 0)
                coop = nb;
            else
                coop = -1;
        }

        bool done = false;
        if (coop > 0) {
            int G = coop * 256;            // 256 CUs on MI355X
            if (G > 4096) G = 4096;
            G &= ~7;                       // multiple of 8 -> phase/XCD pinning
            if (G >= 64) {
                void* args[] = { (void*)&hp };
                if (hipLaunchCooperativeKernel((void*)mega_kernel, dim3(G),
                                               dim3(256), args, 0, stream)
                        == hipSuccess) {
                    done = true;
                } else {
                    coop = -1;             // don't retry cooperative path
                }
            } else {
                coop = -1;
            }
        }
        if (!done) {
            prep2_kernel<<<ZERO_BLOCKS + A_UNITS, 256, 0, stream>>>(hp);
            scatter2_kernel<<<(NE + 255) / 256, 256, 0, stream>>>(hp);
            edge2_kernel<<<C_UNITS, 256, 0, stream>>>(hp);
        }
    } else {
        // fp32 minimal-workspace fallback
        node_kernel_fb<<<A_MLP, 256, 0, stream>>>(hp);
        norm_kernel<VD0><<<(N_NODES * 64 + 255) / 256, 256, 0, stream>>>(hp.vis0, inv0);
        norm_kernel<VD1><<<(N_NODES * 64 + 255) / 256, 256, 0, stream>>>(hp.vis1, inv1);
        edge_kernel<VD0><<<(NE * 64 + 255) / 256, 256, 0, stream>>>(hp.vis0, hp.ei0, inv0, hp.p0w, hp.out);
        edge_kernel<VD1><<<(NE * 64 + 255) / 256, 256, 0, stream>>>(hp.vis1, hp.ei1, inv1, hp.p1w, hp.out);
    }
}

// Round 3
// 261.050 us; speedup vs baseline: 1.8083x; 1.8083x over previous
//
#include <hip/hip_runtime.h>

#define N_NODES 10000
#define NE      80000
#define H       32
#define VD0     2048
#define VD1     256

// fixed-capacity edge buckets (degree is Binomial(80000,1e-4), max ~23 on this
// data; EDGE_CAP=32 with a guaranteed-correct scalar slow-path on overflow)
#define EDGE_CAP 32

// ---- prep dispatch: cur-zero blocks + stage A units ----------------------
#define ZERO_BLOCKS 79                     // ceil(2*N_NODES/256)
#define A_MLP    40                        // node MLP, 256 nodes/block
#define A_NC0    2500                      // normconv graph0, 4 nodes/block
#define A_NC1    2500                      // normconv graph1, 4 nodes/block
#define A_UNITS  (A_MLP + A_NC0 + A_NC1)   // 5040

// ---- edge dispatch -------------------------------------------------------
// graph0: 8 K-phases of 256 elems (512 B), phase = bid & 7. Under round-robin
// block->XCD dispatch each XCD only touches ONE phase slice of vn0 (10 MB
// working set vs 45 MB) -> L2-local src reuse (~8x per chunk, same XCD).
// Coverage of (dst, phase) is exact regardless of the actual XCD mapping.
#define C_PHASES 8
#define C_G0     (C_PHASES * 2500)         // 20000 graph0 units (4 dsts/block)
#define C_UNITS  (C_G0 + 2500)             // + graph1: 4 dsts/block, 512B rows

// ---------------------------------------------------------------------------
// bf16 helpers
// ---------------------------------------------------------------------------
__device__ inline unsigned short f2bf_rne(float f) {
    unsigned int u = __float_as_uint(f);
    u += 0x7fffu + ((u >> 16) & 1u);
    return (unsigned short)(u >> 16);
}
__device__ inline float bflo(unsigned int u) { return __uint_as_float(u << 16); }
__device__ inline float bfhi(unsigned int u) { return __uint_as_float(u & 0xffff0000u); }
__device__ inline float bfs(unsigned short u) { return __uint_as_float((unsigned int)u << 16); }

__device__ inline float dot4_bf16(uint2 a, uint2 b) {
    return bflo(a.x) * bflo(b.x) + bfhi(a.x) * bfhi(b.x)
         + bflo(a.y) * bflo(b.y) + bfhi(a.y) * bfhi(b.y);
}

// ---------------------------------------------------------------------------
// param pack shared by all kernels
// ---------------------------------------------------------------------------
struct KP {
    const float* x;
    const float* vis0; const float* vis1;
    const int* ei0; const int* ei1;
    const float* W_in1; const float* b_in1;
    const float* bn_gamma; const float* bn_beta;
    const float* bn_mean; const float* bn_var;
    const float* prelu_a;
    const float* W_in2; const float* b_in2;
    const float* w_node; const float* b_node;
    const float* W_c0; const float* b_c0;
    const float* W_c1; const float* b_c1;
    const float* w_p0; const float* b_p0;
    const float* w_p1; const float* b_p1;
    float* out; float* p0w; float* p1w;
    unsigned short* vn0; unsigned short* vn1;
    uint2* b0; uint2* b1;
    int* cur0; int* cur1;          // cur0,cur1 CONTIGUOUS (zeroed as one range)
};

// ---------------------------------------------------------------------------
// normconv body: vn[node] = bf16( vis[node] * rsqrt(||vis[node]||^2 + 1e-8) )
// one 64-lane wave per node, row held in registers between passes
// ---------------------------------------------------------------------------
template <int VD>
__device__ inline void normconv_node(const float* __restrict__ vis,
                                     unsigned short* __restrict__ vn,
                                     int node, int lane)
{
    const float4* v = (const float4*)(vis + (size_t)node * VD);
    float4 f[VD / 256];
    float acc = 0.f;
    #pragma unroll
    for (int it = 0; it < VD / 256; it++) {
        f[it] = v[it * 64 + lane];
        acc += f[it].x * f[it].x + f[it].y * f[it].y + f[it].z * f[it].z + f[it].w * f[it].w;
    }
    #pragma unroll
    for (int o = 32; o; o >>= 1) acc += __shfl_xor(acc, o);
    const float inv = rsqrtf(acc + 1e-8f);
    ushort4* o4 = (ushort4*)(vn + (size_t)node * VD);
    #pragma unroll
    for (int it = 0; it < VD / 256; it++) {
        ushort4 r;
        r.x = f2bf_rne(f[it].x * inv);
        r.y = f2bf_rne(f[it].y * inv);
        r.z = f2bf_rne(f[it].z * inv);
        r.w = f2bf_rne(f[it].w * inv);
        o4[it * 64 + lane] = r;
    }
}

// ---------------------------------------------------------------------------
// STAGE A unit: [0,40) node MLP; [40,2540) normconv0; [2540,5040) normconv1
// ---------------------------------------------------------------------------
__device__ inline void stageA_unit(const KP& p, int u, int t)
{
    if (u < A_MLP) {
        __shared__ float sW1[9 * H];
        __shared__ float sW2[H * H];
        __shared__ float sU0[H], sU1[H], sWn[H];
        __shared__ float sB1[H], sB2[H], sSc[H], sSh[H];
        __shared__ float sC;

        for (int i = t; i < 9 * H; i += 256) sW1[i] = p.W_in1[i];
        for (int i = t; i < H * H; i += 256) sW2[i] = p.W_in2[i];
        if (t < H) {
            sB1[t] = p.b_in1[t];
            sB2[t] = p.b_in2[t];
            float sc = p.bn_gamma[t] * rsqrtf(p.bn_var[t] + 1e-5f);
            sSc[t] = sc;
            sSh[t] = p.bn_beta[t] - p.bn_mean[t] * sc;
            sWn[t] = p.w_node[t];
            float u0 = 0.f, u1 = 0.f;
            for (int j = 0; j < H; j++) {
                u0 += p.W_c0[t * H + j] * p.w_p0[j];
                u1 += p.W_c1[t * H + j] * p.w_p1[j];
            }
            sU0[t] = u0; sU1[t] = u1;
        }
        if (t == 0) {
            float c0 = p.b_p0[0], c1 = p.b_p1[0];
            for (int j = 0; j < H; j++) { c0 += p.b_c0[j] * p.w_p0[j]; c1 += p.b_c1[j] * p.w_p1[j]; }
            sC = c0 + c1 + p.b_node[0];
        }
        __syncthreads();

        const float a = p.prelu_a[0];
        const int n = u * 256 + t;
        if (n < N_NODES) {
            float xi[9];
            #pragma unroll
            for (int i = 0; i < 9; i++) xi[i] = p.x[n * 9 + i];

            float tt[H];
            #pragma unroll
            for (int j = 0; j < H; j++) {
                float s = sB1[j];
                #pragma unroll
                for (int i = 0; i < 9; i++) s += xi[i] * sW1[i * H + j];
                s = s * sSc[j] + sSh[j];
                tt[j] = s >= 0.f ? s : a * s;
            }

            float ns = 0.f, p0 = 0.f, p1 = 0.f;
            #pragma unroll
            for (int k = 0; k < H; k++) {
                float h = sB2[k];
                #pragma unroll
                for (int j = 0; j < H; j++) h += tt[j] * sW2[j * H + k];
                ns += h * sWn[k];
                p0 += h * sU0[k];
                p1 += h * sU1[k];
            }
            p.out[n] = ns + sC;
            p.p0w[n] = p0;
            p.p1w[n] = p1;
        }
    } else if (u < A_MLP + A_NC0) {
        const int node = (u - A_MLP) * 4 + (t >> 6);
        normconv_node<VD0>(p.vis0, p.vn0, node, t & 63);
    } else {
        const int node = (u - A_MLP - A_NC0) * 4 + (t >> 6);
        normconv_node<VD1>(p.vis1, p.vn1, node, t & 63);
    }
}

// ---------------------------------------------------------------------------
// STAGE B: bucket-append scatter, one edge slot (both graphs).
// Entry = {src row byte offset, p_weight[src]}. Overflow -> exact slow path.
// ---------------------------------------------------------------------------
__device__ inline void stageB_edge(const KP& p, int e)
{
    {
        const int s = p.ei0[e];
        const int d = p.ei0[NE + e];
        const int pos = atomicAdd(&p.cur0[d], 1);
        if (pos < EDGE_CAP) {
            p.b0[d * EDGE_CAP + pos] = make_uint2((unsigned)(s * (VD0 * 2)),
                                                  __float_as_uint(p.p0w[s]));
        } else {
            const unsigned short* a = p.vn0 + (size_t)s * VD0;
            const unsigned short* c = p.vn0 + (size_t)d * VD0;
            float acc = 0.f;
            for (int i = 0; i < VD0; i++) acc += bfs(a[i]) * bfs(c[i]);
            atomicAdd(&p.out[d], acc * p.p0w[s]);
        }
    }
    {
        const int s = p.ei1[e];
        const int d = p.ei1[NE + e];
        const int pos = atomicAdd(&p.cur1[d], 1);
        if (pos < EDGE_CAP) {
            p.b1[d * EDGE_CAP + pos] = make_uint2((unsigned)(s * (VD1 * 2)),
                                                  __float_as_uint(p.p1w[s]));
        } else {
            const unsigned short* a = p.vn1 + (size_t)s * VD1;
            const unsigned short* c = p.vn1 + (size_t)d * VD1;
            float acc = 0.f;
            for (int i = 0; i < VD1; i++) acc += bfs(a[i]) * bfs(c[i]);
            atomicAdd(&p.out[d], acc * p.p1w[s]);
        }
    }
}

// ---------------------------------------------------------------------------
// STAGE C unit: graph0 [0,20000) = (phase = u&7 for XCD-pinned L2 slices,
// 4 dsts/block, uint2/lane, 8-edge predicated pipeline);
// graph1 [20000,22500) = 4 dsts/block, full 512B row.
// ---------------------------------------------------------------------------
__device__ inline void stageC_unit(const KP& p, int u, int t)
{
    const int lane = t & 63;

    if (u < C_G0) {
        const int phase = u & 7;                  // == XCD id under round-robin
        const int group = u >> 3;
        const int d     = group * 4 + (t >> 6);
        int cnt = p.cur0[d];
        if (cnt <= 0) return;
        cnt = cnt < EDGE_CAP ? cnt : EDGE_CAP;
        const int last = cnt - 1;

        const char* base = (const char*)p.vn0;
        const int koffB  = phase * 512 + lane * 8;     // byte offset into row
        const uint2 dreg = *(const uint2*)(base + d * (VD0 * 2) + koffB);
        const uint2* eb  = p.b0 + d * EDGE_CAP;

        float partial = 0.f;
        for (int j = 0; j < cnt; j += 8) {
            uint2 e[8];
            #pragma unroll
            for (int k = 0; k < 8; k++) {
                int jj = j + k;
                jj = jj > last ? last : jj;
                e[k] = eb[jj];
            }
            uint2 r[8];
            #pragma unroll
            for (int k = 0; k < 8; k++)
                r[k] = *(const uint2*)(base + e[k].x + koffB);
            #pragma unroll
            for (int k = 0; k < 8; k++) {
                const float pw = (j + k <= last) ? __uint_as_float(e[k].y) : 0.f;
                partial += dot4_bf16(dreg, r[k]) * pw;
            }
        }
        #pragma unroll
        for (int o = 32; o; o >>= 1) partial += __shfl_down(partial, o);
        if (lane == 0) atomicAdd(&p.out[d], partial);
    } else {
        const int d = (u - C_G0) * 4 + (t >> 6);
        int cnt = p.cur1[d];
        if (cnt <= 0) return;
        cnt = cnt < EDGE_CAP ? cnt : EDGE_CAP;
        const int last = cnt - 1;

        const char* base = (const char*)p.vn1;
        const int koffB  = lane * 8;
        const uint2 dreg = *(const uint2*)(base + d * (VD1 * 2) + koffB);
        const uint2* eb  = p.b1 + d * EDGE_CAP;

        float partial = 0.f;
        for (int j = 0; j < cnt; j += 8) {
            uint2 e[8];
            #pragma unroll
            for (int k = 0; k < 8; k++) {
                int jj = j + k;
                jj = jj > last ? last : jj;
                e[k] = eb[jj];
            }
            uint2 r[8];
            #pragma unroll
            for (int k = 0; k < 8; k++)
                r[k] = *(const uint2*)(base + e[k].x + koffB);
            #pragma unroll
            for (int k = 0; k < 8; k++) {
                const float pw = (j + k <= last) ? __uint_as_float(e[k].y) : 0.f;
                partial += dot4_bf16(dreg, r[k]) * pw;
            }
        }
        #pragma unroll
        for (int o = 32; o; o >>= 1) partial += __shfl_down(partial, o);
        if (lane == 0) atomicAdd(&p.out[d], partial);
    }
}

// ---------------------------------------------------------------------------
// 3-dispatch pipeline (stream ordering = the cheap grid barrier; R2 showed
// cooperative grid.sync costs ~300 us in cross-XCD cache traffic)
// ---------------------------------------------------------------------------
__global__ __launch_bounds__(256) void prep2_kernel(KP p)
{
    const int b = blockIdx.x, t = threadIdx.x;
    if (b < ZERO_BLOCKS) {
        const int i = b * 256 + t;
        if (i < 2 * N_NODES) p.cur0[i] = 0;
    } else {
        stageA_unit(p, b - ZERO_BLOCKS, t);
    }
}
__global__ __launch_bounds__(256) void scatter2_kernel(KP p)
{
    const int e = blockIdx.x * 256 + threadIdx.x;
    if (e < NE) stageB_edge(p, e);
}
__global__ __launch_bounds__(256) void edge2_kernel(KP p)
{
    stageC_unit(p, blockIdx.x, threadIdx.x);
}

// ---------------------------------------------------------------------------
// fp32 minimal fallback (only if ws can't hold bf16 rows + buckets)
// ---------------------------------------------------------------------------
template <int VD>
__global__ __launch_bounds__(256) void norm_kernel(const float* __restrict__ vis,
                                                   float* __restrict__ inv)
{
    const int wave = (blockIdx.x * 256 + threadIdx.x) >> 6;
    const int lane = threadIdx.x & 63;
    if (wave >= N_NODES) return;
    const float4* v = (const float4*)(vis + (size_t)wave * VD);
    float acc = 0.f;
    #pragma unroll
    for (int it = 0; it < VD / 256; it++) {
        float4 f = v[lane + it * 64];
        acc += f.x * f.x + f.y * f.y + f.z * f.z + f.w * f.w;
    }
    #pragma unroll
    for (int o = 32; o; o >>= 1) acc += __shfl_down(acc, o);
    if (lane == 0) inv[wave] = rsqrtf(acc + 1e-8f);
}

template <int VD>
__global__ __launch_bounds__(256) void edge_kernel(
    const float* __restrict__ vis, const int* __restrict__ ei,
    const float* __restrict__ inv, const float* __restrict__ pz,
    float* __restrict__ out)
{
    const int wave = (blockIdx.x * 256 + threadIdx.x) >> 6;
    const int lane = threadIdx.x & 63;
    if (wave >= NE) return;
    const int src = ei[wave];
    const int dst = ei[NE + wave];
    const float4* va = (const float4*)(vis + (size_t)src * VD);
    const float4* vb = (const float4*)(vis + (size_t)dst * VD);
    float acc = 0.f;
    #pragma unroll
    for (int it = 0; it < VD / 256; it++) {
        float4 fa = va[lane + it * 64];
        float4 fb = vb[lane + it * 64];
        acc += fa.x * fb.x + fa.y * fb.y + fa.z * fb.z + fa.w * fb.w;
    }
    #pragma unroll
    for (int o = 32; o; o >>= 1) acc += __shfl_down(acc, o);
    if (lane == 0) {
        float w = acc * inv[src] * inv[dst];
        atomicAdd(&out[dst], w * pz[src]);
    }
}

__global__ __launch_bounds__(256) void node_kernel_fb(KP p)
{
    stageA_unit(p, (int)blockIdx.x, (int)threadIdx.x);  // only MLP units launched
}

extern "C" void kernel_launch(void* const* d_in, const int* in_sizes, int n_in,
                              void* d_out, int out_size, void* d_ws, size_t ws_size,
                              hipStream_t stream)
{
    KP hp;
    hp.x        = (const float*)d_in[0];
    hp.vis0     = (const float*)d_in[1];
    hp.vis1     = (const float*)d_in[2];
    hp.ei0      = (const int*)d_in[3];
    hp.ei1      = (const int*)d_in[4];
    hp.W_in1    = (const float*)d_in[5];
    hp.b_in1    = (const float*)d_in[6];
    hp.bn_gamma = (const float*)d_in[7];
    hp.bn_beta  = (const float*)d_in[8];
    hp.bn_mean  = (const float*)d_in[9];
    hp.bn_var   = (const float*)d_in[10];
    hp.prelu_a  = (const float*)d_in[11];
    hp.W_in2    = (const float*)d_in[12];
    hp.b_in2    = (const float*)d_in[13];
    hp.w_node   = (const float*)d_in[14];
    hp.b_node   = (const float*)d_in[15];
    hp.W_c0     = (const float*)d_in[16];
    hp.b_c0     = (const float*)d_in[17];
    hp.W_c1     = (const float*)d_in[18];
    hp.b_c1     = (const float*)d_in[19];
    hp.w_p0     = (const float*)d_in[20];
    hp.b_p0     = (const float*)d_in[21];
    hp.w_p1     = (const float*)d_in[22];
    hp.b_p1     = (const float*)d_in[23];
    hp.out      = (float*)d_out;

    // workspace layout — small arrays FIRST (fp32 fallback needs ~160 KB),
    // every chunk a multiple of 16 B
    char* ws = (char*)d_ws;
    hp.p0w  = (float*)ws;                  ws += N_NODES * 4;
    hp.p1w  = (float*)ws;                  ws += N_NODES * 4;
    float* inv0 = (float*)ws;              ws += N_NODES * 4;
    float* inv1 = (float*)ws;              ws += N_NODES * 4;
    hp.vn0  = (unsigned short*)ws;         ws += (size_t)N_NODES * VD0 * 2;
    hp.vn1  = (unsigned short*)ws;         ws += (size_t)N_NODES * VD1 * 2;
    hp.b0   = (uint2*)ws;                  ws += (size_t)N_NODES * EDGE_CAP * 8;
    hp.b1   = (uint2*)ws;                  ws += (size_t)N_NODES * EDGE_CAP * 8;
    hp.cur0 = (int*)ws;                    ws += N_NODES * 4;   // cur0+cur1
    hp.cur1 = (int*)ws;                    ws += N_NODES * 4;   //   contiguous
    const size_t need = (size_t)(ws - (char*)d_ws);

    if (ws_size >= need) {
        prep2_kernel<<<ZERO_BLOCKS + A_UNITS, 256, 0, stream>>>(hp);
        scatter2_kernel<<<(NE + 255) / 256, 256, 0, stream>>>(hp);
        edge2_kernel<<<C_UNITS, 256, 0, stream>>>(hp);
    } else {
        // fp32 minimal-workspace fallback
        node_kernel_fb<<<A_MLP, 256, 0, stream>>>(hp);
        norm_kernel<VD0><<<(N_NODES * 64 + 255) / 256, 256, 0, stream>>>(hp.vis0, inv0);
        norm_kernel<VD1><<<(N_NODES * 64 + 255) / 256, 256, 0, stream>>>(hp.vis1, inv1);
        edge_kernel<VD0><<<(NE * 64 + 255) / 256, 256, 0, stream>>>(hp.vis0, hp.ei0, inv0, hp.p0w, hp.out);
        edge_kernel<VD1><<<(NE * 64 + 255) / 256, 256, 0, stream>>>(hp.vis1, hp.ei1, inv1, hp.p1w, hp.out);
    }
}